// Round 1
// baseline (1523.955 us; speedup 1.0000x reference)
//
#include <hip/hip_runtime.h>
#include <math.h>

#define DD 128          // node embedding dim
#define RR 1024         // root nodes
#define TT 4            // trunk types; encoder TT is the output autoencoder
#define LL 64           // levels
#define MM 2048         // nodes per level
#define NTOT (RR + LL*MM)
#define NB 8            // nodes per workgroup (same encoder type)
#define PAD_SLOTS (MM + 5*NB)      // 2088: each of 5 groups padded to multiple of NB
#define WGS (PAD_SLOTS/NB)         // 261 workgroups per level

// ---------------------------------------------------------------------------
// Group the 2048 nodes of each level by encoder type (0..4), padding each
// group to a multiple of NB with sentinel -1, so every NB-chunk is one type.
// Order within a group is atomic-race dependent but the per-node computation
// is independent -> output is bitwise deterministic regardless.
// ---------------------------------------------------------------------------
__global__ void build_order_kernel(const int* __restrict__ types,
                                   int* __restrict__ order) {
    int l = blockIdx.x;
    int tid = threadIdx.x;
    __shared__ int cnt[5];
    __shared__ int cur[5];
    if (tid < 5) cnt[tid] = 0;
    __syncthreads();
    for (int s = tid; s < PAD_SLOTS; s += blockDim.x)
        order[l*PAD_SLOTS + s] = -1;
    for (int m = tid; m < MM; m += blockDim.x) {
        int t = types[l*MM + m];
        int e = (t >= TT) ? TT : t;
        atomicAdd(&cnt[e], 1);
    }
    __syncthreads();
    if (tid == 0) {
        int off = 0;
        for (int e = 0; e < 5; e++) {
            cur[e] = off;
            off += ((cnt[e] + NB - 1) / NB) * NB;
        }
    }
    __syncthreads();
    for (int m = tid; m < MM; m += blockDim.x) {
        int t = types[l*MM + m];
        int e = (t >= TT) ? TT : t;
        int pos = atomicAdd(&cur[e], 1);
        order[l*PAD_SLOTS + pos] = m;
    }
}

// ---------------------------------------------------------------------------
// One level: each WG processes NB nodes of one encoder type.
// Thread o computes h[o] (layer1, 256 cols) for all NB nodes, then
// (oc = tid&127, half = tid>>7) computes out[oc] for NB/2 nodes.
// ---------------------------------------------------------------------------
__global__ __launch_bounds__(256) void level_kernel(
    const float* __restrict__ W1, const float* __restrict__ b1,
    const float* __restrict__ W2, const float* __restrict__ b2,
    const float* __restrict__ slots, const int* __restrict__ par,
    const int* __restrict__ types, const int* __restrict__ order,
    float* __restrict__ buf, int l)
{
    __shared__ float xs[NB][256];
    __shared__ float hs[NB][256];
    __shared__ int nid[NB];
    __shared__ int etype_s;

    int tid = threadIdx.x;
    int wg  = blockIdx.x;

    if (tid < NB) nid[tid] = order[l*PAD_SLOTS + wg*NB + tid];
    __syncthreads();
    if (tid == 0) {
        int e = -1;
        for (int n = 0; n < NB; n++) {
            if (nid[n] >= 0) {
                int t = types[l*MM + nid[n]];
                e = (t >= TT) ? TT : t;
                break;
            }
        }
        etype_s = e;
    }
    __syncthreads();
    int e = etype_s;
    if (e < 0) return;   // whole chunk is padding

    // ---- gather x = [buf[p0], is_out ? slot_emb : buf[p1]] into LDS ----
    // NB nodes x 64 float4 each (256 floats)
    for (int f = tid; f < NB*64; f += 256) {
        int n = f >> 6, q = f & 63;
        int m = nid[n];
        float4 v = make_float4(0.f, 0.f, 0.f, 0.f);
        if (m >= 0) {
            int gi = l*MM + m;
            if (q < 32) {
                int p0 = par[gi*2 + 0];
                v = ((const float4*)buf)[p0*32 + q];
            } else {
                int t = types[gi];
                if (t >= TT) {
                    int slot = t - TT;   // 0..255 by construction
                    v = ((const float4*)slots)[slot*32 + (q - 32)];
                } else {
                    int p1 = par[gi*2 + 1];
                    v = ((const float4*)buf)[p1*32 + (q - 32)];
                }
            }
        }
        ((float4*)&xs[n][0])[q] = v;
    }
    __syncthreads();

    // ---- layer 1: h = GELU(x @ W1[e] + b1[e]) ----
    {
        int o = tid;
        float acc[NB];
        float bv = b1[e*256 + o];
        #pragma unroll
        for (int n = 0; n < NB; n++) acc[n] = bv;
        const float* Wc = W1 + e*256*256 + o;   // column o, row-stride 256
        for (int i = 0; i < 256; i += 4) {
            float w0 = Wc[(i+0)*256];
            float w1 = Wc[(i+1)*256];
            float w2 = Wc[(i+2)*256];
            float w3 = Wc[(i+3)*256];
            #pragma unroll
            for (int n = 0; n < NB; n++) {
                float4 xv = *(const float4*)&xs[n][i];
                acc[n] = fmaf(xv.x, w0, acc[n]);
                acc[n] = fmaf(xv.y, w1, acc[n]);
                acc[n] = fmaf(xv.z, w2, acc[n]);
                acc[n] = fmaf(xv.w, w3, acc[n]);
            }
        }
        #pragma unroll
        for (int n = 0; n < NB; n++) {
            float h = acc[n];
            float g = 0.5f * h * (1.0f + erff(h * 0.70710678118654752f));
            hs[n][o] = g;
        }
    }
    __syncthreads();

    // ---- layer 2: out = h @ W2[e] + b2[e] ----
    {
        int oc   = tid & 127;
        int half = tid >> 7;          // 0 or 1
        const int HN = NB / 2;
        float acc2[HN];
        float bv = b2[e*128 + oc];
        #pragma unroll
        for (int n = 0; n < HN; n++) acc2[n] = bv;
        const float* Wc = W2 + e*256*128 + oc;  // column oc, row-stride 128
        for (int i = 0; i < 256; i += 4) {
            float w0 = Wc[(i+0)*128];
            float w1 = Wc[(i+1)*128];
            float w2 = Wc[(i+2)*128];
            float w3 = Wc[(i+3)*128];
            #pragma unroll
            for (int n = 0; n < HN; n++) {
                const float* hr = &hs[half*HN + n][i];
                float4 hv = *(const float4*)hr;
                acc2[n] = fmaf(hv.x, w0, acc2[n]);
                acc2[n] = fmaf(hv.y, w1, acc2[n]);
                acc2[n] = fmaf(hv.z, w2, acc2[n]);
                acc2[n] = fmaf(hv.w, w3, acc2[n]);
            }
        }
        int baserow = RR + l*MM;
        #pragma unroll
        for (int n = 0; n < HN; n++) {
            int m = nid[half*HN + n];
            if (m >= 0) buf[(size_t)(baserow + m)*128 + oc] = acc2[n];
        }
    }
}

extern "C" void kernel_launch(void* const* d_in, const int* in_sizes, int n_in,
                              void* d_out, int out_size, void* d_ws, size_t ws_size,
                              hipStream_t stream) {
    const float* root  = (const float*)d_in[0];   // (1024, 128)
    const float* W1    = (const float*)d_in[1];   // (5, 256, 256)
    const float* b1    = (const float*)d_in[2];   // (5, 256)
    const float* W2    = (const float*)d_in[3];   // (5, 256, 128)
    const float* b2    = (const float*)d_in[4];   // (5, 128)
    const float* slots = (const float*)d_in[5];   // (256, 128)
    const int*   par   = (const int*)d_in[6];     // (131072, 2)
    const int*   typ   = (const int*)d_in[7];     // (131072,)
    float* out = (float*)d_out;                   // (132096, 128)
    int* order = (int*)d_ws;                      // 64 * 2088 ints

    // roots -> buf[0:R]
    hipMemcpyAsync(out, root, (size_t)RR * DD * sizeof(float),
                   hipMemcpyDeviceToDevice, stream);

    // group nodes by encoder type per level
    build_order_kernel<<<LL, 256, 0, stream>>>(typ, order);

    // sequential level sweep
    for (int l = 0; l < LL; l++) {
        level_kernel<<<WGS, 256, 0, stream>>>(W1, b1, W2, b2, slots, par, typ,
                                              order, out, l);
    }
}

// Round 2
// 514.719 us; speedup vs baseline: 2.9607x; 2.9607x over previous
//
#include <hip/hip_runtime.h>
#include <math.h>

#define DD 128          // node embedding dim
#define RR 1024         // root nodes
#define TT 4            // trunk types; encoder TT is the output autoencoder
#define LL 64           // levels
#define MM 2048         // nodes per level
#define NBK 16          // nodes per chunk (one MFMA M-tile)
#define PAD16 (MM + 5*NBK)   // 2128 padded slots per level
#define CH (PAD16/NBK)       // 133 chunks per level

typedef __attribute__((ext_vector_type(8))) short short8v;   // 8 bf16 (4 VGPRs)
typedef __attribute__((ext_vector_type(4))) float f32x4;

static __device__ __forceinline__ unsigned short f2bf(float f) {
    unsigned u = __float_as_uint(f);
    unsigned r = (u + 0x7fffu + ((u >> 16) & 1u)) >> 16;   // RNE
    return (unsigned short)r;
}

// ---------------------------------------------------------------------------
// Group nodes of each level by encoder type (0..4), chunks of 16, pad 0xFFFF.
// Within-group order is race-dependent but per-node results are independent,
// so d_out is deterministic.
// ---------------------------------------------------------------------------
__global__ void build_order16(const int* __restrict__ types,
                              unsigned short* __restrict__ order) {
    int l = blockIdx.x, tid = threadIdx.x;
    __shared__ int cnt[5], cur[5];
    if (tid < 5) cnt[tid] = 0;
    __syncthreads();
    for (int s = tid; s < PAD16; s += 256) order[l*PAD16 + s] = 0xFFFFu;
    for (int m = tid; m < MM; m += 256) {
        int t = types[l*MM + m];
        int e = (t >= TT) ? TT : t;
        atomicAdd(&cnt[e], 1);
    }
    __syncthreads();
    if (tid == 0) {
        int off = 0;
        for (int e = 0; e < 5; e++) { cur[e] = off; off += ((cnt[e] + NBK - 1)/NBK)*NBK; }
    }
    __syncthreads();
    for (int m = tid; m < MM; m += 256) {
        int t = types[l*MM + m];
        int e = (t >= TT) ? TT : t;
        int pos = atomicAdd(&cur[e], 1);
        order[l*PAD16 + pos] = (unsigned short)m;
    }
}

// ---------------------------------------------------------------------------
// Pre-convert weights to bf16 in MFMA B-fragment order:
//   W1F[e][nt(16)][kk(8)][lane(64)][j(8)]  with n = nt*16 + (lane&15),
//                                               k = kk*32 + (lane>>4)*8 + j
//   W2F[e][nt(8)][kk(8)][lane(64)][j(8)]   (n < 128)
// -> B-operand load for (nt,kk) is one coalesced 16B/lane dwordx4.
// ---------------------------------------------------------------------------
__global__ void convert_weights(const float* __restrict__ W1,
                                const float* __restrict__ W2,
                                unsigned short* __restrict__ W1F,
                                unsigned short* __restrict__ W2F) {
    int tid = blockIdx.x*256 + threadIdx.x;
    if (tid < 5*16*8*64) {
        int lane = tid & 63;
        int kk = (tid >> 6) & 7;
        int nt = (tid >> 9) & 15;
        int e  = tid >> 13;
        int n  = nt*16 + (lane & 15);
        int k0 = kk*32 + (lane >> 4)*8;
        unsigned short v[8];
        #pragma unroll
        for (int j = 0; j < 8; j++) v[j] = f2bf(W1[(e*256 + k0 + j)*256 + n]);
        *(short8v*)&W1F[tid*8] = *(short8v*)v;
    } else if (tid < 5*16*8*64 + 5*8*8*64) {
        int t = tid - 5*16*8*64;
        int lane = t & 63;
        int kk = (t >> 6) & 7;
        int nt = (t >> 9) & 7;
        int e  = t >> 12;
        int n  = nt*16 + (lane & 15);
        int k0 = kk*32 + (lane >> 4)*8;
        unsigned short v[8];
        #pragma unroll
        for (int j = 0; j < 8; j++) v[j] = f2bf(W2[(e*256 + k0 + j)*128 + n]);
        *(short8v*)&W2F[t*8] = *(short8v*)v;
    }
}

// ---------------------------------------------------------------------------
// One level. WG = 256 threads = 4 waves; 16 same-type nodes per WG.
// Layer1: 16x256 = per wave 4 col-tiles x 8 K-steps of mfma 16x16x32 bf16.
// GELU (exact erf) in registers, H redistributed via LDS to A-fragment order.
// Layer2: 16x128 = per wave 2 col-tiles x 8 K-steps.
// ---------------------------------------------------------------------------
__global__ __launch_bounds__(256) void level_mfma(
    const unsigned short* __restrict__ W1F, const unsigned short* __restrict__ W2F,
    const float* __restrict__ b1, const float* __restrict__ b2,
    const float* __restrict__ slots, const int* __restrict__ par,
    const int* __restrict__ types, const unsigned short* __restrict__ order,
    float* __restrict__ buf, int l)
{
    __shared__ unsigned short axF[8*64*8];   // [kk][lane][j], A-frags of x, 8KB
    __shared__ unsigned short hxF[8*64*8];   // [kk][lane][j], A-frags of h, 8KB
    __shared__ int nid[NBK];
    __shared__ int etype_s;

    int tid = threadIdx.x;
    int wg  = blockIdx.x;

    if (tid < NBK) {
        unsigned short o = order[l*PAD16 + wg*NBK + tid];
        nid[tid] = (o == 0xFFFFu) ? -1 : (int)o;
    }
    __syncthreads();
    if (tid == 0) {
        int e = -1;
        for (int n = 0; n < NBK; n++) {
            if (nid[n] >= 0) { int t = types[l*MM + nid[n]]; e = (t >= TT) ? TT : t; break; }
        }
        etype_s = e;
    }
    __syncthreads();
    int e = etype_s;
    if (e < 0) return;   // fully-padded chunk (uniform exit)

    // ---- gather x = [buf[p0] | is_out ? slot : buf[p1]] into A-frag LDS ----
    {
        int m = tid >> 4, seg = tid & 15;      // node m, 16-float segment seg
        int node = nid[m];
        float vals[16];
        if (node >= 0) {
            int gi = l*MM + node;
            const float* src;
            if (seg < 8) {
                src = buf + (size_t)par[gi*2 + 0]*DD + seg*16;
            } else {
                int t = types[gi];
                if (t >= TT) src = slots + (size_t)(t - TT)*DD + (seg - 8)*16;
                else         src = buf + (size_t)par[gi*2 + 1]*DD + (seg - 8)*16;
            }
            const float4* s4 = (const float4*)src;
            #pragma unroll
            for (int q = 0; q < 4; q++) {
                float4 v = s4[q];
                vals[q*4+0] = v.x; vals[q*4+1] = v.y; vals[q*4+2] = v.z; vals[q*4+3] = v.w;
            }
        } else {
            #pragma unroll
            for (int q = 0; q < 16; q++) vals[q] = 0.f;
        }
        #pragma unroll
        for (int h = 0; h < 2; h++) {
            int k = seg*16 + h*8;
            int kk = k >> 5;
            int lane = m + 16*((k >> 3) & 3);
            unsigned short tmp[8];
            #pragma unroll
            for (int j = 0; j < 8; j++) tmp[j] = f2bf(vals[h*8 + j]);
            *(short8v*)&axF[(kk*64 + lane)*8] = *(short8v*)tmp;
        }
    }
    __syncthreads();

    int w  = tid >> 6;    // wave 0..3
    int lq = tid & 63;    // lane

    // ---- layer 1: H = GELU(X @ W1[e] + b1[e]) ----
    f32x4 acc[4];
    #pragma unroll
    for (int c = 0; c < 4; c++) {
        float bv = b1[e*256 + w*64 + c*16 + (lq & 15)];
        acc[c] = (f32x4){bv, bv, bv, bv};
    }
    {
        const short8v* Ab = (const short8v*)axF;
        #pragma unroll
        for (int kk = 0; kk < 8; kk++) {
            short8v a = Ab[kk*64 + lq];
            #pragma unroll
            for (int c = 0; c < 4; c++) {
                int nt = w*4 + c;
                short8v bfr = *(const short8v*)&W1F[(((e*16 + nt)*8 + kk)*64 + lq)*8];
                acc[c] = __builtin_amdgcn_mfma_f32_16x16x32_bf16(a, bfr, acc[c], 0, 0, 0);
            }
        }
    }
    // GELU + scatter H into A-frag LDS
    #pragma unroll
    for (int c = 0; c < 4; c++) {
        int nh = w*64 + c*16 + (lq & 15);    // hidden index = layer2's k
        int kk2 = nh >> 5;
        int jj  = nh & 7;
        int lhi = 16*((nh >> 3) & 3);
        #pragma unroll
        for (int r = 0; r < 4; r++) {
            int m = (lq >> 4)*4 + r;
            float h = acc[c][r];
            float g = 0.5f*h*(1.0f + erff(h*0.70710678118654752f));
            hxF[(kk2*64 + (m + lhi))*8 + jj] = f2bf(g);
        }
    }
    __syncthreads();

    // ---- layer 2: OUT = H @ W2[e] + b2[e] ----
    f32x4 acc2[2];
    #pragma unroll
    for (int c = 0; c < 2; c++) {
        float bv = b2[e*128 + w*32 + c*16 + (lq & 15)];
        acc2[c] = (f32x4){bv, bv, bv, bv};
    }
    {
        const short8v* Hb = (const short8v*)hxF;
        #pragma unroll
        for (int kk = 0; kk < 8; kk++) {
            short8v a = Hb[kk*64 + lq];
            #pragma unroll
            for (int c = 0; c < 2; c++) {
                int nt = w*2 + c;
                short8v bfr = *(const short8v*)&W2F[(((e*8 + nt)*8 + kk)*64 + lq)*8];
                acc2[c] = __builtin_amdgcn_mfma_f32_16x16x32_bf16(a, bfr, acc2[c], 0, 0, 0);
            }
        }
    }
    int baserow = RR + l*MM;
    #pragma unroll
    for (int r = 0; r < 4; r++) {
        int m = (lq >> 4)*4 + r;
        int node = nid[m];
        if (node >= 0) {
            #pragma unroll
            for (int c = 0; c < 2; c++) {
                int n = w*32 + c*16 + (lq & 15);
                buf[(size_t)(baserow + node)*DD + n] = acc2[c][r];
            }
        }
    }
}

extern "C" void kernel_launch(void* const* d_in, const int* in_sizes, int n_in,
                              void* d_out, int out_size, void* d_ws, size_t ws_size,
                              hipStream_t stream) {
    const float* root  = (const float*)d_in[0];   // (1024, 128)
    const float* W1    = (const float*)d_in[1];   // (5, 256, 256)
    const float* b1    = (const float*)d_in[2];   // (5, 256)
    const float* W2    = (const float*)d_in[3];   // (5, 256, 128)
    const float* b2    = (const float*)d_in[4];   // (5, 128)
    const float* slots = (const float*)d_in[5];   // (256, 128)
    const int*   par   = (const int*)d_in[6];     // (131072, 2)
    const int*   typ   = (const int*)d_in[7];     // (131072,)
    float* out = (float*)d_out;                   // (132096, 128)

    unsigned short* W1F   = (unsigned short*)d_ws;            // 327680 elems (640KB)
    unsigned short* W2F   = W1F + 5*16*8*64*8;                // 163840 elems (320KB)
    unsigned short* order = W2F + 5*8*8*64*8;                 // 64*2128 elems (266KB)

    // roots -> buf[0:R]
    hipMemcpyAsync(out, root, (size_t)RR * DD * sizeof(float),
                   hipMemcpyDeviceToDevice, stream);

    // one-time (per call) prep
    build_order16<<<LL, 256, 0, stream>>>(typ, order);
    convert_weights<<<(5*16*8*64 + 5*8*8*64 + 255)/256, 256, 0, stream>>>(W1, W2, W1F, W2F);

    // sequential level sweep
    for (int l = 0; l < LL; l++) {
        level_mfma<<<CH, 256, 0, stream>>>(W1F, W2F, b1, b2, slots, par, typ,
                                           order, out, l);
    }
}